// Round 3
// baseline (2404.496 us; speedup 1.0000x reference)
//
#include <hip/hip_runtime.h>
#include <hip/hip_bf16.h>
#include <math.h>

#define H_NUM   16
#define D_MODEL 1024
#define D_K     64
#define N_B     2
#define SEQ     2048
#define M_ROWS  (N_B * SEQ)      // 4096
#define NEGVAL  -1.0e9f

typedef short short8 __attribute__((ext_vector_type(8)));
typedef float f32x4 __attribute__((ext_vector_type(4)));

// ---------------------------------------------------------------------------
// Split-bf16 MFMA GEMM: C = A @ W^T + bias, fp32 in/out, ~1e-4 accuracy via
// a = a_hi + a_lo (bf16 RNE split) and 3 MFMAs: hi*hi + hi*lo + lo*hi.
//   A: [M][K] fp32 row-major, W: [N][K] fp32 row-major (torch Linear).
//   SCATTER=0: C[m][n] row-major [M][N].
//   SCATTER=1: C as [B, H, S, dk]: n->(h=n>>6,d=n&63), m->(b=m>>11,s=m&2047).
// Tile: BM=BN=128, BK=32, 512 threads (8 waves, 2x4), wave tile 64x32,
// per-wave acc[4][2] of 16x16 frags. LDS rows padded to 40 bf16 (80 B):
// frag ds_read_b128 start-bank stride 20 -> 2-way conflict (free, m136).
// ---------------------------------------------------------------------------
__device__ inline ushort bf16_hi(float x) {
  return __builtin_bit_cast(ushort, __float2bfloat16(x));
}
__device__ inline float bf16_back(ushort h) {
  return __uint_as_float(((unsigned)h) << 16);
}

template <int SCATTER>
__global__ __launch_bounds__(512) void gemm_mfma(const float* __restrict__ A,
                                                 const float* __restrict__ W,
                                                 const float* __restrict__ bias,
                                                 float* __restrict__ C, int K) {
  __shared__ ushort Ahi[128 * 40];
  __shared__ ushort Alo[128 * 40];
  __shared__ ushort Whi[128 * 40];
  __shared__ ushort Wlo[128 * 40];

  const int tid = threadIdx.x;
  const int rowBase = blockIdx.y * 128;
  const int colBase = blockIdx.x * 128;

  // staging map: thread t, pass j: row = (t>>3)+64j (0..127), k4 = (t&7)*4
  const int srow = tid >> 3;        // 0..63
  const int sk4 = (tid & 7) * 4;    // 0,4,...,28

  // wave/compute map
  const int w = tid >> 6;           // 0..7
  const int wr = w >> 2;            // 0..1 -> rows wr*64
  const int wc = w & 3;             // 0..3 -> cols wc*32
  const int lane = tid & 63;
  const int lr = lane & 15;         // frag row (A) / col (B)
  const int lq = lane >> 4;         // 0..3: k-offset lq*8; C row = lq*4+j

  f32x4 acc[4][2] = {};

  for (int k0 = 0; k0 < K; k0 += 32) {
    // ---- global fp32 -> registers ----
    float4 ga[2], gw[2];
#pragma unroll
    for (int j = 0; j < 2; ++j) {
      const int row = srow + 64 * j;
      ga[j] = *(const float4*)(A + (size_t)(rowBase + row) * K + k0 + sk4);
      gw[j] = *(const float4*)(W + (size_t)(colBase + row) * K + k0 + sk4);
    }
    __syncthreads();  // prior iter's frag reads complete before overwrite
    // ---- split & LDS write ----
#pragma unroll
    for (int j = 0; j < 2; ++j) {
      const int row = srow + 64 * j;
      const int idx = row * 40 + sk4;
      float av[4] = {ga[j].x, ga[j].y, ga[j].z, ga[j].w};
      float wv[4] = {gw[j].x, gw[j].y, gw[j].z, gw[j].w};
      ushort ah[4], al[4], wh[4], wl[4];
#pragma unroll
      for (int i = 0; i < 4; ++i) {
        ah[i] = bf16_hi(av[i]);
        al[i] = bf16_hi(av[i] - bf16_back(ah[i]));
        wh[i] = bf16_hi(wv[i]);
        wl[i] = bf16_hi(wv[i] - bf16_back(wh[i]));
      }
      *(ushort4*)&Ahi[idx] = make_ushort4(ah[0], ah[1], ah[2], ah[3]);
      *(ushort4*)&Alo[idx] = make_ushort4(al[0], al[1], al[2], al[3]);
      *(ushort4*)&Whi[idx] = make_ushort4(wh[0], wh[1], wh[2], wh[3]);
      *(ushort4*)&Wlo[idx] = make_ushort4(wl[0], wl[1], wl[2], wl[3]);
    }
    __syncthreads();

    // ---- fragments (16 B contiguous per lane) ----
    short8 fah[4], fal[4], fwh[2], fwl[2];
#pragma unroll
    for (int mi = 0; mi < 4; ++mi) {
      const int idx = (wr * 64 + mi * 16 + lr) * 40 + lq * 8;
      fah[mi] = *(const short8*)&Ahi[idx];
      fal[mi] = *(const short8*)&Alo[idx];
    }
#pragma unroll
    for (int ni = 0; ni < 2; ++ni) {
      const int idx = (wc * 32 + ni * 16 + lr) * 40 + lq * 8;
      fwh[ni] = *(const short8*)&Whi[idx];
      fwl[ni] = *(const short8*)&Wlo[idx];
    }
    // ---- 3-term split MFMA ----
#pragma unroll
    for (int mi = 0; mi < 4; ++mi)
#pragma unroll
      for (int ni = 0; ni < 2; ++ni) {
        acc[mi][ni] = __builtin_amdgcn_mfma_f32_16x16x32_bf16(
            fah[mi], fwh[ni], acc[mi][ni], 0, 0, 0);
        acc[mi][ni] = __builtin_amdgcn_mfma_f32_16x16x32_bf16(
            fah[mi], fwl[ni], acc[mi][ni], 0, 0, 0);
        acc[mi][ni] = __builtin_amdgcn_mfma_f32_16x16x32_bf16(
            fal[mi], fwh[ni], acc[mi][ni], 0, 0, 0);
      }
  }

  // ---- epilogue: C/D layout col=lane&15, row=(lane>>4)*4+reg ----
  float bv[2];
#pragma unroll
  for (int ni = 0; ni < 2; ++ni) bv[ni] = bias[colBase + wc * 32 + ni * 16 + lr];

#pragma unroll
  for (int mi = 0; mi < 4; ++mi)
#pragma unroll
    for (int ni = 0; ni < 2; ++ni) {
      const int cg = colBase + wc * 32 + ni * 16 + lr;
#pragma unroll
      for (int j = 0; j < 4; ++j) {
        const int rg = rowBase + wr * 64 + mi * 16 + lq * 4 + j;
        const float v = acc[mi][ni][j] + bv[ni];
        if (SCATTER) {
          const int b = rg >> 11;
          const int s = rg & (SEQ - 1);
          const int h = cg >> 6;
          const int d = cg & 63;
          C[(((size_t)b * H_NUM + h) * SEQ + s) * D_K + d] = v;
        } else {
          C[(size_t)rg * D_MODEL + cg] = v;
        }
      }
    }
}

// ---------------------------------------------------------------------------
// fp32 fallback GEMM (not launched; kept for one-line revert if needed)
// ---------------------------------------------------------------------------
template <int SCATTER>
__global__ __launch_bounds__(256) void gemm_bt(const float* __restrict__ A,
                                               const float* __restrict__ W,
                                               const float* __restrict__ bias,
                                               float* __restrict__ C, int K) {
  __shared__ float As[16][68];
  __shared__ float Ws[16][68];
  const int tid = threadIdx.x;
  const int rowBase = blockIdx.y * 64;
  const int colBase = blockIdx.x * 64;
  const int lrow = tid >> 2;
  const int lk4 = (tid & 3) << 2;
  const int tx = tid & 15;
  const int ty = tid >> 4;
  const float* Ap = A + (size_t)(rowBase + lrow) * K + lk4;
  const float* Wp = W + (size_t)(colBase + lrow) * K + lk4;
  float acc[4][4] = {};
  for (int k0 = 0; k0 < K; k0 += 16) {
    float4 a = *(const float4*)(Ap + k0);
    float4 w = *(const float4*)(Wp + k0);
    __syncthreads();
    As[lk4 + 0][lrow] = a.x; As[lk4 + 1][lrow] = a.y;
    As[lk4 + 2][lrow] = a.z; As[lk4 + 3][lrow] = a.w;
    Ws[lk4 + 0][lrow] = w.x; Ws[lk4 + 1][lrow] = w.y;
    Ws[lk4 + 2][lrow] = w.z; Ws[lk4 + 3][lrow] = w.w;
    __syncthreads();
#pragma unroll
    for (int kk = 0; kk < 16; ++kk) {
      float4 av = *(const float4*)&As[kk][ty * 4];
      float4 wv = *(const float4*)&Ws[kk][tx * 4];
      float aa[4] = {av.x, av.y, av.z, av.w};
      float ww[4] = {wv.x, wv.y, wv.z, wv.w};
#pragma unroll
      for (int i = 0; i < 4; ++i)
#pragma unroll
        for (int j = 0; j < 4; ++j) acc[i][j] += aa[i] * ww[j];
    }
  }
  float4 bvv = *(const float4*)(bias + colBase + tx * 4);
  float bb[4] = {bvv.x, bvv.y, bvv.z, bvv.w};
#pragma unroll
  for (int i = 0; i < 4; ++i) {
    const int row = rowBase + ty * 4 + i;
    float4 o;
    o.x = acc[i][0] + bb[0]; o.y = acc[i][1] + bb[1];
    o.z = acc[i][2] + bb[2]; o.w = acc[i][3] + bb[3];
    if (SCATTER) {
      const int b = row >> 11;
      const int s = row & (SEQ - 1);
      const int h = colBase >> 6;
      float* dst = (float*)C + (((size_t)b * H_NUM + h) * SEQ + s) * D_K + tx * 4;
      *(float4*)dst = o;
    } else {
      *(float4*)(C + (size_t)row * D_MODEL + colBase + tx * 4) = o;
    }
  }
}

// ---------------------------------------------------------------------------
// Flash attention (fp32, online softmax fully in registers) — UNCHANGED.
// Q,K,V: [B, H, S, 64].  X out: [B, S, D_MODEL]  (head-merged, ready for W3).
// ---------------------------------------------------------------------------
__global__ __launch_bounds__(256) void flash_attn(const float* __restrict__ Q,
                                                  const float* __restrict__ Km,
                                                  const float* __restrict__ V,
                                                  const int* __restrict__ mask,
                                                  float* __restrict__ X) {
  __shared__ float Qs[32][68];
  __shared__ float Ks[64][68];
  __shared__ float Vs[64][68];
  __shared__ float Ps[32][68];

  const int tid = threadIdx.x;
  const int nqt = SEQ / 32;  // 64
  const int qt = blockIdx.x % nqt;
  const int bh = blockIdx.x / nqt;
  const int b = bh >> 4;

  const float* Qp = Q + ((size_t)bh * SEQ + qt * 32) * D_K;
  const float* Kp = Km + (size_t)bh * SEQ * D_K;
  const float* Vp = V + (size_t)bh * SEQ * D_K;

  {
    const int r = tid >> 3;
    const int c = (tid & 7) * 8;
    float4 q0 = *(const float4*)(Qp + r * D_K + c);
    float4 q1 = *(const float4*)(Qp + r * D_K + c + 4);
    *(float4*)&Qs[r][c] = q0;
    *(float4*)&Qs[r][c + 4] = q1;
  }

  const int r = tid >> 3;
  const int cg = tid & 7;
  const int c0 = cg * 8;

  float m_run = -1e30f;
  float l_run = 0.f;
  float acc[8] = {};

  const int* mrow = mask + ((size_t)b * SEQ + qt * 32 + r) * SEQ;

  for (int kt = 0; kt < SEQ / 64; ++kt) {
    __syncthreads();
#pragma unroll
    for (int j = 0; j < 4; ++j) {
      const int fi = tid * 4 + j;
      const int kr = fi >> 4;
      const int kc = (fi & 15) * 4;
      *(float4*)&Ks[kr][kc] =
          *(const float4*)(Kp + (size_t)(kt * 64 + kr) * D_K + kc);
      *(float4*)&Vs[kr][kc] =
          *(const float4*)(Vp + (size_t)(kt * 64 + kr) * D_K + kc);
    }
    __syncthreads();

    float s[8] = {};
#pragma unroll
    for (int d4 = 0; d4 < 16; ++d4) {
      float4 q4 = *(const float4*)&Qs[r][d4 * 4];
#pragma unroll
      for (int j = 0; j < 8; ++j) {
        const int jj = (j + cg) & 7;
        float4 k4 = *(const float4*)&Ks[c0 + jj][d4 * 4];
        s[jj] += q4.x * k4.x + q4.y * k4.y + q4.z * k4.z + q4.w * k4.w;
      }
    }

    int4 mv0 = *(const int4*)(mrow + kt * 64 + c0);
    int4 mv1 = *(const int4*)(mrow + kt * 64 + c0 + 4);
    int mv[8] = {mv0.x, mv0.y, mv0.z, mv0.w, mv1.x, mv1.y, mv1.z, mv1.w};
    float tmax = -1e30f;
#pragma unroll
    for (int j = 0; j < 8; ++j) {
      s[j] = mv[j] ? s[j] * 0.125f : NEGVAL;
      tmax = fmaxf(tmax, s[j]);
    }
    tmax = fmaxf(tmax, __shfl_xor(tmax, 1));
    tmax = fmaxf(tmax, __shfl_xor(tmax, 2));
    tmax = fmaxf(tmax, __shfl_xor(tmax, 4));

    const float m_new = fmaxf(m_run, tmax);
    const float scale = __expf(m_run - m_new);
    float psum = 0.f;
#pragma unroll
    for (int j = 0; j < 8; ++j) {
      const float p = __expf(s[j] - m_new);
      psum += p;
      Ps[r][c0 + j] = p;
    }
    psum += __shfl_xor(psum, 1);
    psum += __shfl_xor(psum, 2);
    psum += __shfl_xor(psum, 4);
    l_run = l_run * scale + psum;
    m_run = m_new;
    __syncthreads();

#pragma unroll
    for (int j = 0; j < 8; ++j) acc[j] *= scale;
#pragma unroll
    for (int k4 = 0; k4 < 16; ++k4) {
      float4 p4 = *(const float4*)&Ps[r][k4 * 4];
      float pa[4] = {p4.x, p4.y, p4.z, p4.w};
#pragma unroll
      for (int kk = 0; kk < 4; ++kk) {
        float4 va = *(const float4*)&Vs[k4 * 4 + kk][c0];
        float4 vb = *(const float4*)&Vs[k4 * 4 + kk][c0 + 4];
        acc[0] += pa[kk] * va.x;
        acc[1] += pa[kk] * va.y;
        acc[2] += pa[kk] * va.z;
        acc[3] += pa[kk] * va.w;
        acc[4] += pa[kk] * vb.x;
        acc[5] += pa[kk] * vb.y;
        acc[6] += pa[kk] * vb.z;
        acc[7] += pa[kk] * vb.w;
      }
    }
  }

  const float inv = 1.f / l_run;
  const int h = bh & 15;
  const int qrow = qt * 32 + r;
  float* xp = X + ((size_t)b * SEQ + qrow) * D_MODEL + h * D_K + c0;
  float4 o0 = {acc[0] * inv, acc[1] * inv, acc[2] * inv, acc[3] * inv};
  float4 o1 = {acc[4] * inv, acc[5] * inv, acc[6] * inv, acc[7] * inv};
  *(float4*)xp = o0;
  *(float4*)(xp + 4) = o1;
}

// ---------------------------------------------------------------------------
extern "C" void kernel_launch(void* const* d_in, const int* in_sizes, int n_in,
                              void* d_out, int out_size, void* d_ws,
                              size_t ws_size, hipStream_t stream) {
  const float* query = (const float*)d_in[0];
  const float* key   = (const float*)d_in[1];
  const float* value = (const float*)d_in[2];
  const int*   mask  = (const int*)d_in[3];
  const float* W0 = (const float*)d_in[4];
  const float* b0 = (const float*)d_in[5];
  const float* W1 = (const float*)d_in[6];
  const float* b1 = (const float*)d_in[7];
  const float* W2 = (const float*)d_in[8];
  const float* b2 = (const float*)d_in[9];
  const float* W3 = (const float*)d_in[10];
  const float* b3 = (const float*)d_in[11];
  float* out = (float*)d_out;

  float* ws = (float*)d_ws;
  const size_t HSZ = (size_t)N_B * H_NUM * SEQ * D_K;  // 4,194,304 floats
  float* Qb = ws;
  float* Kb = ws + HSZ;
  float* Vb = ws + 2 * HSZ;
  float* Xb = ws + 3 * HSZ;  // total 64 MiB of d_ws

  dim3 gg(D_MODEL / 128, M_ROWS / 128);  // 8 x 32 = 256 blocks
  gemm_mfma<1><<<gg, 512, 0, stream>>>(query, W0, b0, Qb, D_MODEL);
  gemm_mfma<1><<<gg, 512, 0, stream>>>(key, W1, b1, Kb, D_MODEL);
  gemm_mfma<1><<<gg, 512, 0, stream>>>(value, W2, b2, Vb, D_MODEL);

  flash_attn<<<N_B * H_NUM * (SEQ / 32), 256, 0, stream>>>(Qb, Kb, Vb, mask,
                                                           Xb);

  gemm_mfma<0><<<gg, 512, 0, stream>>>(Xb, W3, b3, out, D_MODEL);
}

// Round 6
// 560.757 us; speedup vs baseline: 4.2879x; 4.2879x over previous
//
#include <hip/hip_runtime.h>
#include <hip/hip_bf16.h>
#include <math.h>

#define H_NUM   16
#define D_MODEL 1024
#define D_K     64
#define N_B     2
#define SEQ     2048
#define M_ROWS  (N_B * SEQ)      // 4096
#define NEGVAL  -1.0e9f

typedef short short8 __attribute__((ext_vector_type(8)));
typedef float f32x4 __attribute__((ext_vector_type(4)));

__device__ inline short bf16s(float x) {
  return (short)__builtin_bit_cast(ushort, __float2bfloat16(x));
}
__device__ inline float bf16f(short h) {
  return __uint_as_float(((unsigned)(ushort)h) << 16);
}

// ---------------------------------------------------------------------------
// Split-bf16 MFMA GEMM: C = A @ W^T + bias; fp32 in, ~1e-4 accuracy via
// a = a_hi + a_lo and 3 MFMAs (hh + hl + lh). Validated round 3.
//  MODE 0: C0 = fp32 [M][D_MODEL] row-major.
//  MODE 1: C0/C1 = bf16 hi/lo, scatter [B,H,S,64] (Q,K for attention).
//  MODE 2: C0/C1 = bf16 hi/lo, TRANSPOSED [B,H,64,S] (V^T for attention).
//          Uses swapped MFMA operands so D-col tracks the s-dim -> the
//          transposed global store stays lane-contiguous.
// Tile: BM=BN=128, BK=32, 512 thr (8 waves 2x4), wave tile 64x32.
// ---------------------------------------------------------------------------
template <int MODE>
__global__ __launch_bounds__(512) void gemm_mfma(const float* __restrict__ A,
                                                 const float* __restrict__ W,
                                                 const float* __restrict__ bias,
                                                 void* __restrict__ C0,
                                                 void* __restrict__ C1, int K) {
  __shared__ ushort Ahi[128 * 40];
  __shared__ ushort Alo[128 * 40];
  __shared__ ushort Whi[128 * 40];
  __shared__ ushort Wlo[128 * 40];

  const int tid = threadIdx.x;
  const int rowBase = blockIdx.y * 128;
  const int colBase = blockIdx.x * 128;

  const int srow = tid >> 3;        // 0..63
  const int sk4 = (tid & 7) * 4;    // 0,4,...,28

  const int w = tid >> 6;           // 0..7
  const int wr = w >> 2;            // 0..1
  const int wc = w & 3;             // 0..3
  const int lane = tid & 63;
  const int lr = lane & 15;
  const int lq = lane >> 4;

  f32x4 acc[4][2] = {};

  for (int k0 = 0; k0 < K; k0 += 32) {
    float4 ga[2], gw[2];
#pragma unroll
    for (int j = 0; j < 2; ++j) {
      const int row = srow + 64 * j;
      ga[j] = *(const float4*)(A + (size_t)(rowBase + row) * K + k0 + sk4);
      gw[j] = *(const float4*)(W + (size_t)(colBase + row) * K + k0 + sk4);
    }
    __syncthreads();
#pragma unroll
    for (int j = 0; j < 2; ++j) {
      const int row = srow + 64 * j;
      const int idx = row * 40 + sk4;
      float av[4] = {ga[j].x, ga[j].y, ga[j].z, ga[j].w};
      float wv[4] = {gw[j].x, gw[j].y, gw[j].z, gw[j].w};
      ushort ah[4], al[4], wh[4], wl[4];
#pragma unroll
      for (int i = 0; i < 4; ++i) {
        ah[i] = (ushort)bf16s(av[i]);
        al[i] = (ushort)bf16s(av[i] - bf16f((short)ah[i]));
        wh[i] = (ushort)bf16s(wv[i]);
        wl[i] = (ushort)bf16s(wv[i] - bf16f((short)wh[i]));
      }
      *(ushort4*)&Ahi[idx] = make_ushort4(ah[0], ah[1], ah[2], ah[3]);
      *(ushort4*)&Alo[idx] = make_ushort4(al[0], al[1], al[2], al[3]);
      *(ushort4*)&Whi[idx] = make_ushort4(wh[0], wh[1], wh[2], wh[3]);
      *(ushort4*)&Wlo[idx] = make_ushort4(wl[0], wl[1], wl[2], wl[3]);
    }
    __syncthreads();

    short8 fah[4], fal[4], fwh[2], fwl[2];
#pragma unroll
    for (int mi = 0; mi < 4; ++mi) {
      const int idx = (wr * 64 + mi * 16 + lr) * 40 + lq * 8;
      fah[mi] = *(const short8*)&Ahi[idx];
      fal[mi] = *(const short8*)&Alo[idx];
    }
#pragma unroll
    for (int ni = 0; ni < 2; ++ni) {
      const int idx = (wc * 32 + ni * 16 + lr) * 40 + lq * 8;
      fwh[ni] = *(const short8*)&Whi[idx];
      fwl[ni] = *(const short8*)&Wlo[idx];
    }
#pragma unroll
    for (int mi = 0; mi < 4; ++mi)
#pragma unroll
      for (int ni = 0; ni < 2; ++ni) {
        if constexpr (MODE == 2) {
          // swapped operands: D-row <- W-row (d), D-col <- A-row (s)
          acc[mi][ni] = __builtin_amdgcn_mfma_f32_16x16x32_bf16(
              fwh[ni], fah[mi], acc[mi][ni], 0, 0, 0);
          acc[mi][ni] = __builtin_amdgcn_mfma_f32_16x16x32_bf16(
              fwh[ni], fal[mi], acc[mi][ni], 0, 0, 0);
          acc[mi][ni] = __builtin_amdgcn_mfma_f32_16x16x32_bf16(
              fwl[ni], fah[mi], acc[mi][ni], 0, 0, 0);
        } else {
          acc[mi][ni] = __builtin_amdgcn_mfma_f32_16x16x32_bf16(
              fah[mi], fwh[ni], acc[mi][ni], 0, 0, 0);
          acc[mi][ni] = __builtin_amdgcn_mfma_f32_16x16x32_bf16(
              fah[mi], fwl[ni], acc[mi][ni], 0, 0, 0);
          acc[mi][ni] = __builtin_amdgcn_mfma_f32_16x16x32_bf16(
              fal[mi], fwh[ni], acc[mi][ni], 0, 0, 0);
        }
      }
  }

  if constexpr (MODE == 2) {
    // D-row = n-dir (d), D-col = m-dir (s)
    float bvv[2][4];
#pragma unroll
    for (int ni = 0; ni < 2; ++ni)
#pragma unroll
      for (int j = 0; j < 4; ++j)
        bvv[ni][j] = bias[colBase + wc * 32 + ni * 16 + lq * 4 + j];
#pragma unroll
    for (int mi = 0; mi < 4; ++mi)
#pragma unroll
      for (int ni = 0; ni < 2; ++ni) {
        const int m = rowBase + wr * 64 + mi * 16 + lr;  // s-dim
        const int b = m >> 11;
        const int s = m & (SEQ - 1);
#pragma unroll
        for (int j = 0; j < 4; ++j) {
          const int n = colBase + wc * 32 + ni * 16 + lq * 4 + j;  // d-dim
          const int h = n >> 6;
          const int dk = n & 63;
          const float v = acc[mi][ni][j] + bvv[ni][j];
          const short hi = bf16s(v);
          const short lo = bf16s(v - bf16f(hi));
          const size_t off = (((size_t)b * H_NUM + h) * D_K + dk) * SEQ + s;
          ((short*)C0)[off] = hi;
          ((short*)C1)[off] = lo;
        }
      }
  } else {
    float bv[2];
#pragma unroll
    for (int ni = 0; ni < 2; ++ni)
      bv[ni] = bias[colBase + wc * 32 + ni * 16 + lr];
#pragma unroll
    for (int mi = 0; mi < 4; ++mi)
#pragma unroll
      for (int ni = 0; ni < 2; ++ni) {
        const int cg = colBase + wc * 32 + ni * 16 + lr;
#pragma unroll
        for (int j = 0; j < 4; ++j) {
          const int rg = rowBase + wr * 64 + mi * 16 + lq * 4 + j;
          const float v = acc[mi][ni][j] + bv[ni];
          if constexpr (MODE == 1) {
            const int b = rg >> 11;
            const int s = rg & (SEQ - 1);
            const int h = cg >> 6;
            const int dk = cg & 63;
            const short hi = bf16s(v);
            const short lo = bf16s(v - bf16f(hi));
            const size_t off = (((size_t)b * H_NUM + h) * SEQ + s) * D_K + dk;
            ((short*)C0)[off] = hi;
            ((short*)C1)[off] = lo;
          } else {
            ((float*)C0)[(size_t)rg * D_MODEL + cg] = v;
          }
        }
      }
  }
}

// ---------------------------------------------------------------------------
// Mask pre-pass: flags[b*S + row] bit kt = 1 iff mask[b][row][kt*64..+64]
// are ALL nonzero. One wave per row.
// ---------------------------------------------------------------------------
__global__ __launch_bounds__(256) void mask_flags(const int* __restrict__ mask,
                                                  uint* __restrict__ flags) {
  const int row = blockIdx.x * 4 + (threadIdx.x >> 6);  // [0, 4096)
  const int lane = threadIdx.x & 63;
  const int kt = lane >> 1, half = lane & 1;
  const int4* p = (const int4*)(mask + (size_t)row * SEQ + kt * 64 + half * 32);
  int ok = 1;
#pragma unroll
  for (int i = 0; i < 8; ++i) {
    int4 v = p[i];
    ok &= (v.x != 0) & (v.y != 0) & (v.z != 0) & (v.w != 0);
  }
  ok &= __shfl_xor(ok, 1);
  unsigned long long bl = __ballot(ok != 0);
  if (lane == 0) {
    uint fw = 0;
#pragma unroll
    for (int k = 0; k < 32; ++k) fw |= (uint)((bl >> (2 * k)) & 1ULL) << k;
    flags[row] = fw;
  }
}

// ---------------------------------------------------------------------------
// Flash attention, split-bf16 MFMA (3-term, near-fp32 accuracy).
// Inputs pre-split: Qhi/Qlo,Khi/Klo [B,H,S,64]; V^T hi/lo [B,H,64,S].
// Block: 512 thr = 8 waves, Q-tile 128 (16 rows/wave, Q-frags in regs),
// KV-tile 64. Online softmax in regs (shfl over 16-lane frag groups);
// P split to bf16 hi/lo via wave-private LDS (no barrier needed).
// X out: fp32 [B*S][D_MODEL], head-merged for the final GEMM.
// ---------------------------------------------------------------------------
#define QBLK 128
#define KSTR 72

__global__ __launch_bounds__(512, 2) void flash_mfma(
    const short* __restrict__ Qhi, const short* __restrict__ Qlo,
    const short* __restrict__ Khi, const short* __restrict__ Klo,
    const short* __restrict__ Vthi, const short* __restrict__ Vtlo,
    const int* __restrict__ mask, const uint* __restrict__ flags,
    float* __restrict__ X) {
  __shared__ short Kh[64 * KSTR], Kl[64 * KSTR];
  __shared__ short Vh[64 * KSTR], Vl[64 * KSTR];
  __shared__ short Ph[QBLK * KSTR], Pl[QBLK * KSTR];
  __shared__ uint fl[QBLK];

  const int tid = threadIdx.x;
  const int w = tid >> 6;
  const int lane = tid & 63;
  const int lr = lane & 15;
  const int lq = lane >> 4;
  const int qt = blockIdx.x & 15;   // 2048/128 q-tiles
  const int bh = blockIdx.x >> 4;   // 0..31
  const int b = bh >> 4;
  const int h = bh & 15;

  if (tid < QBLK) fl[tid] = flags[b * SEQ + qt * QBLK + tid];
  __syncthreads();

  // Q fragments: held in registers for the whole kernel
  const int qrow = qt * QBLK + w * 16 + lr;
  const short* qbh = Qhi + ((size_t)bh * SEQ + qrow) * D_K;
  const short* qbl = Qlo + ((size_t)bh * SEQ + qrow) * D_K;
  short8 qh[2], ql[2];
#pragma unroll
  for (int c = 0; c < 2; ++c) {
    qh[c] = *(const short8*)(qbh + c * 32 + lq * 8);
    ql[c] = *(const short8*)(qbl + c * 32 + lq * 8);
  }

  const short* kbh = Khi + (size_t)bh * SEQ * D_K;
  const short* kbl = Klo + (size_t)bh * SEQ * D_K;
  const short* vbh = Vthi + (size_t)bh * D_K * SEQ;
  const short* vbl = Vtlo + (size_t)bh * D_K * SEQ;

  f32x4 o[4] = {};
  float m_run[4] = {-1e30f, -1e30f, -1e30f, -1e30f};
  float l_run[4] = {};

  const int srow = tid >> 3;        // 0..63
  const int sc = (tid & 7) * 8;     // 0..56

  for (int kt = 0; kt < SEQ / 64; ++kt) {
    __syncthreads();  // prior tile's frag reads done
    *(short8*)&Kh[srow * KSTR + sc] =
        *(const short8*)(kbh + (size_t)(kt * 64 + srow) * D_K + sc);
    *(short8*)&Kl[srow * KSTR + sc] =
        *(const short8*)(kbl + (size_t)(kt * 64 + srow) * D_K + sc);
    *(short8*)&Vh[srow * KSTR + sc] =
        *(const short8*)(vbh + (size_t)srow * SEQ + kt * 64 + sc);
    *(short8*)&Vl[srow * KSTR + sc] =
        *(const short8*)(vbl + (size_t)srow * SEQ + kt * 64 + sc);
    __syncthreads();

    // ---- S = Q K^T (3-term split) ----
    f32x4 sa[4] = {};
#pragma unroll
    for (int c = 0; c < 2; ++c)
#pragma unroll
      for (int n = 0; n < 4; ++n) {
        const int idx = (n * 16 + lr) * KSTR + c * 32 + lq * 8;
        short8 kh = *(const short8*)&Kh[idx];
        short8 klv = *(const short8*)&Kl[idx];
        sa[n] = __builtin_amdgcn_mfma_f32_16x16x32_bf16(qh[c], kh, sa[n], 0, 0, 0);
        sa[n] = __builtin_amdgcn_mfma_f32_16x16x32_bf16(qh[c], klv, sa[n], 0, 0, 0);
        sa[n] = __builtin_amdgcn_mfma_f32_16x16x32_bf16(ql[c], kh, sa[n], 0, 0, 0);
      }

    // ---- scale + mask ----
    const int r0 = w * 16 + lq * 4;
    int fb = (int)((fl[r0 + 0] >> kt) & 1) & (int)((fl[r0 + 1] >> kt) & 1) &
             (int)((fl[r0 + 2] >> kt) & 1) & (int)((fl[r0 + 3] >> kt) & 1);
    if (__builtin_expect(!__all(fb), 0)) {
#pragma unroll
      for (int n = 0; n < 4; ++n)
#pragma unroll
        for (int j = 0; j < 4; ++j) {
          int mv = mask[((size_t)b * SEQ + qt * QBLK + r0 + j) * SEQ + kt * 64 +
                        n * 16 + lr];
          sa[n][j] = mv ? sa[n][j] * 0.125f : NEGVAL;
        }
    } else {
#pragma unroll
      for (int n = 0; n < 4; ++n)
#pragma unroll
        for (int j = 0; j < 4; ++j) sa[n][j] *= 0.125f;
    }

    // ---- online softmax (rows j, values across n and 16 lanes) ----
    float scl[4];
#pragma unroll
    for (int j = 0; j < 4; ++j) {
      float t = fmaxf(fmaxf(sa[0][j], sa[1][j]), fmaxf(sa[2][j], sa[3][j]));
      t = fmaxf(t, __shfl_xor(t, 1));
      t = fmaxf(t, __shfl_xor(t, 2));
      t = fmaxf(t, __shfl_xor(t, 4));
      t = fmaxf(t, __shfl_xor(t, 8));
      const float mn = fmaxf(m_run[j], t);
      scl[j] = __expf(m_run[j] - mn);
      m_run[j] = mn;
    }
    float ps[4] = {};
#pragma unroll
    for (int n = 0; n < 4; ++n)
#pragma unroll
      for (int j = 0; j < 4; ++j) {
        const float p = __expf(sa[n][j] - m_run[j]);
        ps[j] += p;
        const short phi = bf16s(p);
        Ph[(r0 + j) * KSTR + n * 16 + lr] = phi;
        Pl[(r0 + j) * KSTR + n * 16 + lr] = bf16s(p - bf16f(phi));
      }
#pragma unroll
    for (int j = 0; j < 4; ++j) {
      float t = ps[j];
      t += __shfl_xor(t, 1);
      t += __shfl_xor(t, 2);
      t += __shfl_xor(t, 4);
      t += __shfl_xor(t, 8);
      l_run[j] = l_run[j] * scl[j] + t;
    }
#pragma unroll
    for (int n = 0; n < 4; ++n)
#pragma unroll
      for (int j = 0; j < 4; ++j) o[n][j] *= scl[j];

    // ---- PV (wave-private P; same-wave LDS RAW -> no barrier) ----
#pragma unroll
    for (int c = 0; c < 2; ++c) {
      const int pidx = (w * 16 + lr) * KSTR + c * 32 + lq * 8;
      short8 pah = *(const short8*)&Ph[pidx];
      short8 pal = *(const short8*)&Pl[pidx];
#pragma unroll
      for (int n = 0; n < 4; ++n) {
        const int vidx = (n * 16 + lr) * KSTR + c * 32 + lq * 8;
        short8 vh = *(const short8*)&Vh[vidx];
        short8 vl = *(const short8*)&Vl[vidx];
        o[n] = __builtin_amdgcn_mfma_f32_16x16x32_bf16(pah, vh, o[n], 0, 0, 0);
        o[n] = __builtin_amdgcn_mfma_f32_16x16x32_bf16(pah, vl, o[n], 0, 0, 0);
        o[n] = __builtin_amdgcn_mfma_f32_16x16x32_bf16(pal, vh, o[n], 0, 0, 0);
      }
    }
  }

  float inv[4];
#pragma unroll
  for (int j = 0; j < 4; ++j) inv[j] = 1.f / l_run[j];
#pragma unroll
  for (int n = 0; n < 4; ++n)
#pragma unroll
    for (int j = 0; j < 4; ++j) {
      X[((size_t)b * SEQ + qt * QBLK + w * 16 + lq * 4 + j) * D_MODEL + h * D_K +
        n * 16 + lr] = o[n][j] * inv[j];
    }
}

// ---------------------------------------------------------------------------
extern "C" void kernel_launch(void* const* d_in, const int* in_sizes, int n_in,
                              void* d_out, int out_size, void* d_ws,
                              size_t ws_size, hipStream_t stream) {
  const float* query = (const float*)d_in[0];
  const float* key   = (const float*)d_in[1];
  const float* value = (const float*)d_in[2];
  const int*   mask  = (const int*)d_in[3];
  const float* W0 = (const float*)d_in[4];
  const float* b0 = (const float*)d_in[5];
  const float* W1 = (const float*)d_in[6];
  const float* b1 = (const float*)d_in[7];
  const float* W2 = (const float*)d_in[8];
  const float* b2 = (const float*)d_in[9];
  const float* W3 = (const float*)d_in[10];
  const float* b3 = (const float*)d_in[11];
  float* out = (float*)d_out;

  // ws layout (64 MiB total, same budget as validated round 3):
  // 6 bf16 tensors of HSZ shorts + X fp32.
  const size_t HSZ = (size_t)N_B * H_NUM * SEQ * D_K;  // 4,194,304
  short* Qh = (short*)d_ws;
  short* Ql = Qh + HSZ;
  short* Kh = Qh + 2 * HSZ;
  short* Kl = Qh + 3 * HSZ;
  short* Vth = Qh + 4 * HSZ;
  short* Vtl = Qh + 5 * HSZ;
  float* Xb = (float*)(Qh + 6 * HSZ);  // 16 MiB

  // mask flags live in the tail of d_out (16 KB), overwritten by the final
  // GEMM afterwards (stream-serial, safe).
  uint* flags = (uint*)d_out + (out_size - N_B * SEQ);

  mask_flags<<<M_ROWS / 4, 256, 0, stream>>>(mask, flags);

  dim3 gg(D_MODEL / 128, M_ROWS / 128);  // 8 x 32
  gemm_mfma<1><<<gg, 512, 0, stream>>>(query, W0, b0, Qh, Ql, D_MODEL);
  gemm_mfma<1><<<gg, 512, 0, stream>>>(key, W1, b1, Kh, Kl, D_MODEL);
  gemm_mfma<2><<<gg, 512, 0, stream>>>(value, W2, b2, Vth, Vtl, D_MODEL);

  flash_mfma<<<(SEQ / QBLK) * N_B * H_NUM, 512, 0, stream>>>(
      Qh, Ql, Kh, Kl, Vth, Vtl, mask, flags, Xb);

  gemm_mfma<0><<<gg, 512, 0, stream>>>(Xb, W3, b3, out, nullptr, D_MODEL);
}

// Round 11
// 477.224 us; speedup vs baseline: 5.0385x; 1.1750x over previous
//
#include <hip/hip_runtime.h>
#include <hip/hip_bf16.h>
#include <math.h>

#define H_NUM   16
#define D_MODEL 1024
#define D_K     64
#define N_B     2
#define SEQ     2048
#define M_ROWS  (N_B * SEQ)      // 4096
#define NEGVAL  -1.0e9f

typedef short short8 __attribute__((ext_vector_type(8)));
typedef float f32x4 __attribute__((ext_vector_type(4)));

__device__ inline short bf16s(float x) {
  return (short)__builtin_bit_cast(ushort, __float2bfloat16(x));
}
__device__ inline float bf16f(short h) {
  return __uint_as_float(((unsigned)(ushort)h) << 16);
}

// async global->LDS DMA, 16 B per lane. Global addr is PER-LANE; LDS dest is
// wave-uniform base + lane*16.
__device__ inline void gl_lds16(const void* g, void* l) {
  __builtin_amdgcn_global_load_lds(
      (const __attribute__((address_space(1))) unsigned int*)g,
      (__attribute__((address_space(3))) unsigned int*)l, 16, 0, 0);
}

// ---------------------------------------------------------------------------
// Fragment-order global layouts (single source of truth, used by producer
// epilogues AND the flash kernel):
//  Q/K  [bh, s16tile, c, lane, 8]:  chunk16B idx = ((bh*128 + (s>>4))*2 + (d>>5))*64
//                                   + ((d>>3)&3)*16 + (s&15);  short = d&7
//  V^T  [bh, kt64, d16tile, c, lane, 8]: idx = (((bh*32+(s>>6))*4+(d>>4))*2
//                                   + ((s>>5)&1))*64 + ((s>>3)&3)*16 + (d&15); short = s&7
// A wave's ds_read_b128 of any fragment is then lane-linear (conflict-free),
// and staging is 1 global_load_lds per wave per 512-short block.
// ---------------------------------------------------------------------------

// ---------------------------------------------------------------------------
// Split-bf16 MFMA GEMM: C = (A @ W^T + bias) * scale; 3 MFMAs (hh+hl+lh).
//  MODE 0: C0 = fp32 [M][D_MODEL] row-major (scale=1).
//  MODE 1: C0/C1 = bf16 hi/lo in frag-order Q/K layout (scale=0.125 for Q).
//  MODE 2: C0/C1 = bf16 hi/lo in frag-order V^T layout (swapped MFMA operands
//          so the d-dim lands on D-rows).
// Tile: BM=BN=128, BK=32, 512 thr (8 waves 2x4), wave tile 64x32.
// r8: staging software-pipelined — prefetch k0+32 issued after the LDS-write
// barrier, consumed next iteration (latency hidden under 24 MFMAs).
// ---------------------------------------------------------------------------
template <int MODE>
__global__ __launch_bounds__(512) void gemm_mfma(const float* __restrict__ A,
                                                 const float* __restrict__ W,
                                                 const float* __restrict__ bias,
                                                 void* __restrict__ C0,
                                                 void* __restrict__ C1, int K,
                                                 float scale) {
  __shared__ ushort Ahi[128 * 40];
  __shared__ ushort Alo[128 * 40];
  __shared__ ushort Whi[128 * 40];
  __shared__ ushort Wlo[128 * 40];

  const int tid = threadIdx.x;
  const int rowBase = blockIdx.y * 128;
  const int colBase = blockIdx.x * 128;

  const int srow = tid >> 3;        // 0..63
  const int sk4 = (tid & 7) * 4;    // 0,4,...,28

  const int w = tid >> 6;           // 0..7
  const int wr = w >> 2;            // 0..1
  const int wc = w & 3;             // 0..3
  const int lane = tid & 63;
  const int lr = lane & 15;
  const int lq = lane >> 4;

  const float* Ap = A + (size_t)(rowBase + srow) * K + sk4;
  const float* Wp = W + (size_t)(colBase + srow) * K + sk4;

  f32x4 acc[4][2] = {};

  // prologue: load k-step 0
  float4 ga[2], gw[2];
#pragma unroll
  for (int j = 0; j < 2; ++j) {
    ga[j] = *(const float4*)(Ap + (size_t)(64 * j) * K);
    gw[j] = *(const float4*)(Wp + (size_t)(64 * j) * K);
  }

  for (int k0 = 0; k0 < K; k0 += 32) {
    __syncthreads();  // prior iter's frag reads complete before overwrite
    // ---- split & LDS write (from regs loaded last iter) ----
#pragma unroll
    for (int j = 0; j < 2; ++j) {
      const int row = srow + 64 * j;
      const int idx = row * 40 + sk4;
      float av[4] = {ga[j].x, ga[j].y, ga[j].z, ga[j].w};
      float wv[4] = {gw[j].x, gw[j].y, gw[j].z, gw[j].w};
      ushort ah[4], al[4], wh[4], wl[4];
#pragma unroll
      for (int i = 0; i < 4; ++i) {
        ah[i] = (ushort)bf16s(av[i]);
        al[i] = (ushort)bf16s(av[i] - bf16f((short)ah[i]));
        wh[i] = (ushort)bf16s(wv[i]);
        wl[i] = (ushort)bf16s(wv[i] - bf16f((short)wh[i]));
      }
      *(ushort4*)&Ahi[idx] = make_ushort4(ah[0], ah[1], ah[2], ah[3]);
      *(ushort4*)&Alo[idx] = make_ushort4(al[0], al[1], al[2], al[3]);
      *(ushort4*)&Whi[idx] = make_ushort4(wh[0], wh[1], wh[2], wh[3]);
      *(ushort4*)&Wlo[idx] = make_ushort4(wl[0], wl[1], wl[2], wl[3]);
    }
    __syncthreads();

    // ---- prefetch next k-step; latency hides under the MFMAs below ----
    if (k0 + 32 < K) {
#pragma unroll
      for (int j = 0; j < 2; ++j) {
        ga[j] = *(const float4*)(Ap + (size_t)(64 * j) * K + k0 + 32);
        gw[j] = *(const float4*)(Wp + (size_t)(64 * j) * K + k0 + 32);
      }
    }

    short8 fah[4], fal[4], fwh[2], fwl[2];
#pragma unroll
    for (int mi = 0; mi < 4; ++mi) {
      const int idx = (wr * 64 + mi * 16 + lr) * 40 + lq * 8;
      fah[mi] = *(const short8*)&Ahi[idx];
      fal[mi] = *(const short8*)&Alo[idx];
    }
#pragma unroll
    for (int ni = 0; ni < 2; ++ni) {
      const int idx = (wc * 32 + ni * 16 + lr) * 40 + lq * 8;
      fwh[ni] = *(const short8*)&Whi[idx];
      fwl[ni] = *(const short8*)&Wlo[idx];
    }
#pragma unroll
    for (int mi = 0; mi < 4; ++mi)
#pragma unroll
      for (int ni = 0; ni < 2; ++ni) {
        if constexpr (MODE == 2) {
          acc[mi][ni] = __builtin_amdgcn_mfma_f32_16x16x32_bf16(
              fwh[ni], fah[mi], acc[mi][ni], 0, 0, 0);
          acc[mi][ni] = __builtin_amdgcn_mfma_f32_16x16x32_bf16(
              fwh[ni], fal[mi], acc[mi][ni], 0, 0, 0);
          acc[mi][ni] = __builtin_amdgcn_mfma_f32_16x16x32_bf16(
              fwl[ni], fah[mi], acc[mi][ni], 0, 0, 0);
        } else {
          acc[mi][ni] = __builtin_amdgcn_mfma_f32_16x16x32_bf16(
              fah[mi], fwh[ni], acc[mi][ni], 0, 0, 0);
          acc[mi][ni] = __builtin_amdgcn_mfma_f32_16x16x32_bf16(
              fah[mi], fwl[ni], acc[mi][ni], 0, 0, 0);
          acc[mi][ni] = __builtin_amdgcn_mfma_f32_16x16x32_bf16(
              fal[mi], fwh[ni], acc[mi][ni], 0, 0, 0);
        }
      }
  }

  if constexpr (MODE == 2) {
    // D-row = d-dim, D-col = s-dim
    float bvv[2][4];
#pragma unroll
    for (int ni = 0; ni < 2; ++ni)
#pragma unroll
      for (int j = 0; j < 4; ++j)
        bvv[ni][j] = bias[colBase + wc * 32 + ni * 16 + lq * 4 + j];
#pragma unroll
    for (int mi = 0; mi < 4; ++mi)
#pragma unroll
      for (int ni = 0; ni < 2; ++ni) {
        const int m = rowBase + wr * 64 + mi * 16 + lr;  // s-dim
        const int b = m >> 11;
        const int s = m & (SEQ - 1);
#pragma unroll
        for (int j = 0; j < 4; ++j) {
          const int n = colBase + wc * 32 + ni * 16 + lq * 4 + j;  // d-dim
          const int h = n >> 6;
          const int dk = n & 63;
          const float v = (acc[mi][ni][j] + bvv[ni][j]) * scale;
          const short hi = bf16s(v);
          const short lo = bf16s(v - bf16f(hi));
          const int bh = b * H_NUM + h;
          const size_t off =
              (((((size_t)bh * 32 + (s >> 6)) * 4 + (dk >> 4)) * 2 +
                ((s >> 5) & 1)) * 512) +
              ((s >> 3) & 3) * 128 + (dk & 15) * 8 + (s & 7);
          ((short*)C0)[off] = hi;
          ((short*)C1)[off] = lo;
        }
      }
  } else {
    float bv[2];
#pragma unroll
    for (int ni = 0; ni < 2; ++ni)
      bv[ni] = bias[colBase + wc * 32 + ni * 16 + lr];
#pragma unroll
    for (int mi = 0; mi < 4; ++mi)
#pragma unroll
      for (int ni = 0; ni < 2; ++ni) {
        const int cg = colBase + wc * 32 + ni * 16 + lr;
#pragma unroll
        for (int j = 0; j < 4; ++j) {
          const int rg = rowBase + wr * 64 + mi * 16 + lq * 4 + j;
          const float v = (acc[mi][ni][j] + bv[ni]) * scale;
          if constexpr (MODE == 1) {
            const int b = rg >> 11;
            const int s = rg & (SEQ - 1);
            const int h = cg >> 6;
            const int dk = cg & 63;
            const short hi = bf16s(v);
            const short lo = bf16s(v - bf16f(hi));
            const int bh = b * H_NUM + h;
            const size_t off =
                ((((size_t)bh * 128 + (s >> 4)) * 2 + (dk >> 5)) * 512) +
                ((dk >> 3) & 3) * 128 + (s & 15) * 8 + (dk & 7);
            ((short*)C0)[off] = hi;
            ((short*)C1)[off] = lo;
          } else {
            ((float*)C0)[(size_t)rg * D_MODEL + cg] = v;
          }
        }
      }
  }
}

// ---------------------------------------------------------------------------
// Mask pre-pass: flags[b*S + row] bit kt = 1 iff mask[b][row][kt*64..+64]
// are ALL nonzero. One wave per row.  (unchanged, validated r6)
// ---------------------------------------------------------------------------
__global__ __launch_bounds__(256) void mask_flags(const int* __restrict__ mask,
                                                  uint* __restrict__ flags) {
  const int row = blockIdx.x * 4 + (threadIdx.x >> 6);  // [0, 4096)
  const int lane = threadIdx.x & 63;
  const int kt = lane >> 1, half = lane & 1;
  const int4* p = (const int4*)(mask + (size_t)row * SEQ + kt * 64 + half * 32);
  int ok = 1;
#pragma unroll
  for (int i = 0; i < 8; ++i) {
    int4 v = p[i];
    ok &= (v.x != 0) & (v.y != 0) & (v.z != 0) & (v.w != 0);
  }
  ok &= __shfl_xor(ok, 1);
  unsigned long long bl = __ballot(ok != 0);
  if (lane == 0) {
    uint fw = 0;
#pragma unroll
    for (int k = 0; k < 32; ++k) fw |= (uint)((bl >> (2 * k)) & 1ULL) << k;
    flags[row] = fw;
  }
}

// ---------------------------------------------------------------------------
// Flash attention, split-bf16 MFMA. Frag-order inputs; Q pre-scaled by 1/8.
// 512 thr = 8 waves; Q-tile 128 (16 rows/wave, Q in regs); KV-tile 64.
// K/V double-buffered via global_load_lds DMA; ONE barrier per tile:
//   issue DMA(kt+1 -> buf^1); compute from buf; barrier (drain + release buf).
// All frag ds_reads are lane-linear (conflict-free by construction).
// (byte-identical to the round-6/7/8/9 submission)
// ---------------------------------------------------------------------------
#define QBLK 128

__global__ __launch_bounds__(512, 2) void flash_mfma(
    const short* __restrict__ Qhg, const short* __restrict__ Qlg,
    const short* __restrict__ Khg, const short* __restrict__ Klg,
    const short* __restrict__ Vhg, const short* __restrict__ Vlg,
    const int* __restrict__ mask, const uint* __restrict__ flags,
    float* __restrict__ X) {
  // [buf][tensor: 0=Kh 1=Kl 2=Vh 3=Vl][4096 shorts]  = 64 KB
  __shared__ __attribute__((aligned(16))) short KV[2][4][4096];
  __shared__ __attribute__((aligned(16))) short Ph[QBLK * 64];  // 16 KB
  __shared__ __attribute__((aligned(16))) short Pl[QBLK * 64];  // 16 KB
  __shared__ uint fl[QBLK];

  const int tid = threadIdx.x;
  const int w = tid >> 6;
  const int lane = tid & 63;
  const int lr = lane & 15;
  const int lq = lane >> 4;
  const int qt = blockIdx.x & 15;   // 2048/128 q-tiles
  const int bh = blockIdx.x >> 4;   // 0..31
  const int b = bh >> 4;

  if (tid < QBLK) fl[tid] = flags[b * SEQ + qt * QBLK + tid];

  // Q fragments (frag-order layout -> coalesced b128 loads), in regs all kernel
  short8 qh[2], ql[2];
#pragma unroll
  for (int c = 0; c < 2; ++c) {
    const size_t qi = (((size_t)bh * 128 + qt * 8 + w) * 2 + c) * 512 + lane * 8;
    qh[c] = *(const short8*)(Qhg + qi);
    ql[c] = *(const short8*)(Qlg + qi);
  }

  // stage tile 0 into buf 0 (4 DMA per wave)
  {
    const size_t kblk = ((size_t)bh * 128 + 0 * 4 + (w >> 1)) * 2 + (w & 1);
    const size_t vblk = (((size_t)bh * 32 + 0) * 4 + (w >> 1)) * 2 + (w & 1);
    gl_lds16(Khg + kblk * 512 + lane * 8, &KV[0][0][w * 512]);
    gl_lds16(Klg + kblk * 512 + lane * 8, &KV[0][1][w * 512]);
    gl_lds16(Vhg + vblk * 512 + lane * 8, &KV[0][2][w * 512]);
    gl_lds16(Vlg + vblk * 512 + lane * 8, &KV[0][3][w * 512]);
  }
  __syncthreads();  // tile0 landed; fl visible

  f32x4 o[4] = {};
  float m_run[4] = {-1e30f, -1e30f, -1e30f, -1e30f};
  float l_run[4] = {};
  const int r0 = w * 16 + lq * 4;

  const int NT = SEQ / 64;  // 32
  for (int kt = 0; kt < NT; ++kt) {
    const int cur = kt & 1;
    if (kt + 1 < NT) {  // prefetch next tile into the other buffer
      const size_t kblk =
          ((size_t)bh * 128 + (kt + 1) * 4 + (w >> 1)) * 2 + (w & 1);
      const size_t vblk =
          (((size_t)bh * 32 + (kt + 1)) * 4 + (w >> 1)) * 2 + (w & 1);
      gl_lds16(Khg + kblk * 512 + lane * 8, &KV[cur ^ 1][0][w * 512]);
      gl_lds16(Klg + kblk * 512 + lane * 8, &KV[cur ^ 1][1][w * 512]);
      gl_lds16(Vhg + vblk * 512 + lane * 8, &KV[cur ^ 1][2][w * 512]);
      gl_lds16(Vlg + vblk * 512 + lane * 8, &KV[cur ^ 1][3][w * 512]);
    }

    // ---- S = Q K^T (3-term split); lane-linear frag reads ----
    f32x4 sa[4] = {};
#pragma unroll
    for (int c = 0; c < 2; ++c)
#pragma unroll
      for (int n = 0; n < 4; ++n) {
        const int off = (n * 2 + c) * 512 + lane * 8;
        short8 kh = *(const short8*)&KV[cur][0][off];
        short8 kl = *(const short8*)&KV[cur][1][off];
        sa[n] = __builtin_amdgcn_mfma_f32_16x16x32_bf16(qh[c], kh, sa[n], 0, 0, 0);
        sa[n] = __builtin_amdgcn_mfma_f32_16x16x32_bf16(qh[c], kl, sa[n], 0, 0, 0);
        sa[n] = __builtin_amdgcn_mfma_f32_16x16x32_bf16(ql[c], kh, sa[n], 0, 0, 0);
      }

    // ---- mask (Q pre-scaled; fast path = no-op) ----
    int fb = (int)((fl[r0 + 0] >> kt) & 1) & (int)((fl[r0 + 1] >> kt) & 1) &
             (int)((fl[r0 + 2] >> kt) & 1) & (int)((fl[r0 + 3] >> kt) & 1);
    if (__builtin_expect(!__all(fb), 0)) {
#pragma unroll
      for (int n = 0; n < 4; ++n)
#pragma unroll
        for (int j = 0; j < 4; ++j) {
          int mv = mask[((size_t)b * SEQ + qt * QBLK + r0 + j) * SEQ + kt * 64 +
                        n * 16 + lr];
          if (!mv) sa[n][j] = NEGVAL;
        }
    }

    // ---- online softmax (row j; reduce over n and 16 lanes) ----
    float scl[4];
#pragma unroll
    for (int j = 0; j < 4; ++j) {
      float t = fmaxf(fmaxf(sa[0][j], sa[1][j]), fmaxf(sa[2][j], sa[3][j]));
      t = fmaxf(t, __shfl_xor(t, 1));
      t = fmaxf(t, __shfl_xor(t, 2));
      t = fmaxf(t, __shfl_xor(t, 4));
      t = fmaxf(t, __shfl_xor(t, 8));
      const float mn = fmaxf(m_run[j], t);
      scl[j] = __expf(m_run[j] - mn);
      m_run[j] = mn;
    }
    float ps[4] = {};
    // P chunk-linear layout: short = (w*2+(n>>1))*512 + ((n&1)*2+(lr>>3))*128
    //                                + (lq*4+j)*8 + (lr&7)
#pragma unroll
    for (int n = 0; n < 4; ++n) {
      const int pbase = (w * 2 + (n >> 1)) * 512 + ((n & 1) * 2 + (lr >> 3)) * 128 + (lr & 7);
#pragma unroll
      for (int j = 0; j < 4; ++j) {
        const float p = __expf(sa[n][j] - m_run[j]);
        ps[j] += p;
        const short phi = bf16s(p);
        Ph[pbase + (lq * 4 + j) * 8] = phi;
        Pl[pbase + (lq * 4 + j) * 8] = bf16s(p - bf16f(phi));
      }
    }
#pragma unroll
    for (int j = 0; j < 4; ++j) {
      float t = ps[j];
      t += __shfl_xor(t, 1);
      t += __shfl_xor(t, 2);
      t += __shfl_xor(t, 4);
      t += __shfl_xor(t, 8);
      l_run[j] = l_run[j] * scl[j] + t;
    }
#pragma unroll
    for (int n = 0; n < 4; ++n)
#pragma unroll
      for (int j = 0; j < 4; ++j) o[n][j] *= scl[j];

    // ---- PV (wave-private P, same-wave LDS RAW; lane-linear reads) ----
#pragma unroll
    for (int c = 0; c < 2; ++c) {
      const int poff = (w * 2 + c) * 512 + lane * 8;
      short8 pah = *(const short8*)&Ph[poff];
      short8 pal = *(const short8*)&Pl[poff];
#pragma unroll
      for (int n = 0; n < 4; ++n) {
        const int voff = (n * 2 + c) * 512 + lane * 8;
        short8 vh = *(const short8*)&KV[cur][2][voff];
        short8 vl = *(const short8*)&KV[cur][3][voff];
        o[n] = __builtin_amdgcn_mfma_f32_16x16x32_bf16(pah, vh, o[n], 0, 0, 0);
        o[n] = __builtin_amdgcn_mfma_f32_16x16x32_bf16(pah, vl, o[n], 0, 0, 0);
        o[n] = __builtin_amdgcn_mfma_f32_16x16x32_bf16(pal, vh, o[n], 0, 0, 0);
      }
    }

    __syncthreads();  // drain DMA (tile kt+1 ready) + all waves done with buf cur
  }

  float inv[4];
#pragma unroll
  for (int j = 0; j < 4; ++j) inv[j] = 1.f / l_run[j];
  const int h = bh & 15;
#pragma unroll
  for (int n = 0; n < 4; ++n)
#pragma unroll
    for (int j = 0; j < 4; ++j) {
      X[((size_t)b * SEQ + qt * QBLK + w * 16 + lq * 4 + j) * D_MODEL +
        h * D_K + n * 16 + lr] = o[n][j] * inv[j];
    }
}

// ---------------------------------------------------------------------------
extern "C" void kernel_launch(void* const* d_in, const int* in_sizes, int n_in,
                              void* d_out, int out_size, void* d_ws,
                              size_t ws_size, hipStream_t stream) {
  const float* query = (const float*)d_in[0];
  const float* key   = (const float*)d_in[1];
  const float* value = (const float*)d_in[2];
  const int*   mask  = (const int*)d_in[3];
  const float* W0 = (const float*)d_in[4];
  const float* b0 = (const float*)d_in[5];
  const float* W1 = (const float*)d_in[6];
  const float* b1 = (const float*)d_in[7];
  const float* W2 = (const float*)d_in[8];
  const float* b2 = (const float*)d_in[9];
  const float* W3 = (const float*)d_in[10];
  const float* b3 = (const float*)d_in[11];
  float* out = (float*)d_out;

  const size_t HSZ = (size_t)N_B * H_NUM * SEQ * D_K;  // 4,194,304 shorts/tensor
  short* Qh = (short*)d_ws;
  short* Ql = Qh + HSZ;
  short* Kh = Qh + 2 * HSZ;
  short* Kl = Qh + 3 * HSZ;
  short* Vth = Qh + 4 * HSZ;
  short* Vtl = Qh + 5 * HSZ;
  float* Xb = (float*)(Qh + 6 * HSZ);  // 16 MiB

  // mask flags in the tail of d_out (16 KB), rewritten every call,
  // overwritten by the final GEMM afterwards (stream-serial, safe).
  uint* flags = (uint*)d_out + (out_size - N_B * SEQ);

  mask_flags<<<M_ROWS / 4, 256, 0, stream>>>(mask, flags);

  dim3 gg(D_MODEL / 128, M_ROWS / 128);  // 8 x 32
  gemm_mfma<1><<<gg, 512, 0, stream>>>(query, W0, b0, Qh, Ql, D_MODEL, 0.125f);
  gemm_mfma<1><<<gg, 512, 0, stream>>>(key, W1, b1, Kh, Kl, D_MODEL, 1.0f);
  gemm_mfma<2><<<gg, 512, 0, stream>>>(value, W2, b2, Vth, Vtl, D_MODEL, 1.0f);

  flash_mfma<<<(SEQ / QBLK) * N_B * H_NUM, 512, 0, stream>>>(
      Qh, Ql, Kh, Kl, Vth, Vtl, mask, flags, Xb);

  gemm_mfma<0><<<gg, 512, 0, stream>>>(Xb, W3, b3, out, nullptr, D_MODEL, 1.0f);
}